// Round 6
// baseline (1934.359 us; speedup 1.0000x reference)
//
#include <hip/hip_runtime.h>
#include <hip/hip_bf16.h>
#include <cstdint>
#include <cstddef>

// CFnetFilter: w_ij = segment_sum(ssp(ssp(dijk@W1+b1)@W2+b2), seg_j)
//
// R6 = R5 (persistent-wave streaming pipeline) + TBAA fix. R5's failure was
// type-punned LDS access: reduce read LDS as uint32_t while writes were
// __bf16 -> strict aliasing let the compiler reorder next-iteration h' writes
// past this iteration's reduce reads of the SAME bytes (LDS tile reused every
// iteration). All punned accesses now go through may_alias typedefs.
//
// Structure: 1024 blocks x 4 waves, all resident. Each wave owns a contiguous
// chunk of 30-31 16-row tiles; per tile: prefetch next tile's dijk into regs
// (in flight across compute), GEMM1 -> softplus -> h in LDS (4KB/wave,
// swizzled), GEMM2 -> softplus -> wijk in LDS, segmented reduce carrying
// (a0,a1,cur) across tiles. Interior segments are wave-exclusive -> plain
// float2 stores; chunk-boundary segments -> atomicAdd. No barriers.

typedef float f32x4 __attribute__((ext_vector_type(4)));
typedef __bf16 bf16x8 __attribute__((ext_vector_type(8)));

// may_alias views for LDS type-punning (the R5 bug fix)
typedef uint32_t u32a    __attribute__((may_alias));
typedef bf16x8   bf16x8a __attribute__((may_alias));
typedef __bf16   bf16a   __attribute__((may_alias));

static constexpr int   N_TRIPLES = 2000000;
static constexpr int   DIM       = 128;
static constexpr int   NSEG      = 100000;
static constexpr int   NBLOCKS   = 1024;
static constexpr int   NWAVES    = NBLOCKS * 4;               // 4096
static constexpr int   M_TILES   = N_TRIPLES / 16;            // 125000
static constexpr int   BASE_T    = M_TILES / NWAVES;          // 30
static constexpr int   REM_T     = M_TILES - BASE_T * NWAVES; // 2120
static constexpr float LOG2F_    = 0.6931471805599453f;

// softplus only (layer-1's -log2 folded into b2'; layer 2 subtracts it)
__device__ __forceinline__ float sp_(float x) {
  float e = __expf(-fabsf(x));
  return fmaxf(x, 0.0f) + __logf(1.0f + e);
}

// Transpose W1,W2 [k][n] f32 -> WT [n][k] bf16 (MFMA B-frags contiguous in k)
__global__ void wt_kernel(const float* __restrict__ W1, const float* __restrict__ W2,
                          __bf16* __restrict__ WT) {
  int t = blockIdx.x * 256 + threadIdx.x;   // 0..16383
  int k = t >> 7;
  int n = t & 127;
  WT[n * 128 + k]         = (__bf16)W1[t];
  WT[16384 + n * 128 + k] = (__bf16)W2[t];
}

// b2'[n] = b2[n] - log2 * sum_k W2[k][n]
__global__ void bias_kernel(const float* __restrict__ W2, const float* __restrict__ b2,
                            float* __restrict__ b2p) {
  int n = threadIdx.x;
  float s = 0.0f;
  #pragma unroll 8
  for (int k = 0; k < 128; ++k) s += W2[k * 128 + n];
  b2p[n] = b2[n] - LOG2F_ * s;
}

__global__ __launch_bounds__(256, 4) void fused_kernel(
    const float* __restrict__ dijk, const int* __restrict__ seg,
    const __bf16* __restrict__ WT,
    const float* __restrict__ b1v, const float* __restrict__ b2p,
    float* __restrict__ out)
{
  __shared__ __bf16 hbuf[4 * 16 * DIM];   // 16 KB; private 4 KB per wave

  const int tid  = threadIdx.x;
  const int lane = tid & 63;
  const int wave = tid >> 6;
  const int l15  = lane & 15;
  const int g    = lane >> 4;

  const int wid  = blockIdx.x * 4 + wave;
  const int n_t  = BASE_T + (wid < REM_T ? 1 : 0);
  const int t0   = wid * BASE_T + (wid < REM_T ? wid : REM_T);
  const int row0 = t0 * 16;               // first row of this wave's chunk

  char* hb = (char*)hbuf + wave * 4096;   // this wave's h/wijk tile (16 rows)

  // biases for this lane's 8 column slots (col = nt*16 + l15)
  float bias1[8], bias2[8];
  #pragma unroll
  for (int nt = 0; nt < 8; ++nt) {
    bias1[nt] = b1v[nt * 16 + l15];
    bias2[nt] = b2p[nt * 16 + l15];
  }

  const __bf16* WT1 = WT;
  const __bf16* WT2 = WT + 16384;

  // per-lane A pointer: row (row0 + l15), k-base g*8
  const float* ap = dijk + (size_t)(row0 + l15) * DIM + g * 8;

  const int srow0 = __builtin_amdgcn_readfirstlane(row0);
  const int* sp = seg + srow0;            // uniform -> scalar loads
  const int first_seg = sp[0];
  const int colb = lane * 2;              // this lane's output column pair

  // prologue: load tile 0 (8 x dwordx4 per lane = 16 rows x 128 f32 per wave)
  f32x4 va[8];
  #pragma unroll
  for (int q = 0; q < 4; ++q) {
    va[2 * q]     = *(const f32x4*)(ap + q * 32);
    va[2 * q + 1] = *(const f32x4*)(ap + q * 32 + 4);
  }

  float a0 = 0.0f, a1 = 0.0f;
  int cur = first_seg;

  for (int it = 0; it < n_t; ++it) {
    // convert current tile to bf16 A-fragments (frees va registers)
    bf16x8 afrag[4];
    #pragma unroll
    for (int ks = 0; ks < 4; ++ks) {
      f32x4 v0 = va[2 * ks], v1 = va[2 * ks + 1];
      bf16x8 t8;
      t8[0] = (__bf16)v0[0]; t8[1] = (__bf16)v0[1]; t8[2] = (__bf16)v0[2]; t8[3] = (__bf16)v0[3];
      t8[4] = (__bf16)v1[0]; t8[5] = (__bf16)v1[1]; t8[6] = (__bf16)v1[2]; t8[7] = (__bf16)v1[3];
      afrag[ks] = t8;
    }

    // issue NEXT tile's loads now -- in flight across this iteration's compute
    const float* apn = ap + (it + 1 < n_t ? 16 * DIM : 0);  // clamp last (data unused)
    #pragma unroll
    for (int q = 0; q < 4; ++q) {
      va[2 * q]     = *(const f32x4*)(apn + q * 32);
      va[2 * q + 1] = *(const f32x4*)(apn + q * 32 + 4);
    }
    ap = apn;

    // ---------------- GEMM1: h' = softplus(A @ W1 + b1) ----------------
    f32x4 acc[8];
    #pragma unroll
    for (int nt = 0; nt < 8; ++nt) acc[nt] = (f32x4){0.f, 0.f, 0.f, 0.f};
    #pragma unroll
    for (int ks = 0; ks < 4; ++ks) {
      #pragma unroll
      for (int nt = 0; nt < 8; ++nt) {
        bf16x8 bfrag = *(const bf16x8*)(WT1 + (nt * 16 + l15) * DIM + ks * 32 + g * 8);
        acc[nt] = __builtin_amdgcn_mfma_f32_16x16x32_bf16(afrag[ks], bfrag, acc[nt], 0, 0, 0);
      }
    }
    // softplus + h' -> LDS (bf16, XOR-swizzled). C/D: row=g*4+j, col=nt*16+l15
    #pragma unroll
    for (int nt = 0; nt < 8; ++nt) {
      #pragma unroll
      for (int j = 0; j < 4; ++j) {
        int row = g * 4 + j;
        int col = nt * 16 + l15;
        float hv = sp_(acc[nt][j] + bias1[nt]);
        *(bf16a*)(hb + row * 256 + ((col * 2) ^ ((row & 7) << 4))) = (__bf16)hv;
      }
    }

    // ---------------- GEMM2: w = softplus(h' @ W2 + b2') - log2 ----------------
    f32x4 acc2[8];
    #pragma unroll
    for (int nt = 0; nt < 8; ++nt) acc2[nt] = (f32x4){0.f, 0.f, 0.f, 0.f};
    #pragma unroll
    for (int ks = 0; ks < 4; ++ks) {
      // A-frag of h: row=l15, k bytes [ks*64+g*16, +16), same swizzle
      bf16x8 hf = *(const bf16x8a*)(hb + l15 * 256 + ((ks * 64 + g * 16) ^ ((l15 & 7) << 4)));
      #pragma unroll
      for (int nt = 0; nt < 8; ++nt) {
        bf16x8 bfrag = *(const bf16x8*)(WT2 + (nt * 16 + l15) * DIM + ks * 32 + g * 8);
        acc2[nt] = __builtin_amdgcn_mfma_f32_16x16x32_bf16(hf, bfrag, acc2[nt], 0, 0, 0);
      }
    }
    // softplus + wijk -> same LDS tile (in-order DS pipe: reads above done)
    #pragma unroll
    for (int nt = 0; nt < 8; ++nt) {
      #pragma unroll
      for (int j = 0; j < 4; ++j) {
        int row = g * 4 + j;
        int col = nt * 16 + l15;
        float wv = sp_(acc2[nt][j] + bias2[nt]) - LOG2F_;
        *(bf16a*)(hb + row * 256 + ((col * 2) ^ ((row & 7) << 4))) = (__bf16)wv;
      }
    }

    // ---------------- segmented reduce for this tile (carry across tiles) ----
    uint32_t v[16];
    #pragma unroll
    for (int k = 0; k < 16; ++k)
      v[k] = *(const u32a*)(hb + k * 256 + ((colb * 2) ^ ((k & 7) << 4)));
    const int* st = sp + it * 16;
    #pragma unroll
    for (int k = 0; k < 16; ++k) {
      int s = st[k];                      // uniform -> scalar load
      if (s != cur) {                     // wave-uniform branch
        if (cur == first_seg) {           // may extend into previous wave's chunk
          atomicAdd(out + (size_t)cur * DIM + colb,     a0);
          atomicAdd(out + (size_t)cur * DIM + colb + 1, a1);
        } else {                          // interior: wave-exclusive -> store
          float2 w2; w2.x = a0; w2.y = a1;
          *(float2*)(out + (size_t)cur * DIM + colb) = w2;
        }
        a0 = 0.0f; a1 = 0.0f; cur = s;
      }
      uint32_t w = v[k];
      a0 += __uint_as_float(w << 16);          // bf16 lo -> f32
      a1 += __uint_as_float(w & 0xffff0000u);  // bf16 hi -> f32
    }
  }

  // final flush: last segment may extend into next wave's chunk -> atomic
  atomicAdd(out + (size_t)cur * DIM + colb,     a0);
  atomicAdd(out + (size_t)cur * DIM + colb + 1, a1);
}

extern "C" void kernel_launch(void* const* d_in, const int* in_sizes, int n_in,
                              void* d_out, int out_size, void* d_ws, size_t ws_size,
                              hipStream_t stream) {
  const float* dijk = (const float*)d_in[0];
  const int*   seg  = (const int*)d_in[1];
  const float* W1   = (const float*)d_in[2];
  const float* b1   = (const float*)d_in[3];
  const float* W2   = (const float*)d_in[4];
  const float* b2   = (const float*)d_in[5];
  float* out = (float*)d_out;

  float*  b2p = (float*)d_ws;                       // 128 f32
  __bf16* WT  = (__bf16*)((char*)d_ws + 1024);      // 2 * 128*128 bf16 = 64 KB

  // empty segments must be exactly 0; interior stores overwrite, boundary
  // atomics accumulate; memset re-zeroes every replay (graph-safe).
  hipMemsetAsync(out, 0, (size_t)NSEG * DIM * sizeof(float), stream);

  wt_kernel<<<64, 256, 0, stream>>>(W1, W2, WT);
  bias_kernel<<<1, 128, 0, stream>>>(W2, b2, b2p);

  fused_kernel<<<NBLOCKS, 256, 0, stream>>>(dijk, seg, WT, b1, b2p, out);
}

// Round 7
// 1467.485 us; speedup vs baseline: 1.3181x; 1.3181x over previous
//
#include <hip/hip_runtime.h>
#include <hip/hip_bf16.h>
#include <cstdint>
#include <cstddef>

// CFnetFilter: w_ij = segment_sum(ssp(ssp(dijk@W1+b1)@W2+b2), seg_j)
//
// R7: persistent-wave streaming with global_load_lds DMA (no VGPR staging).
// R6 post-mortem: reg-staged prefetch (va[16]) overflowed the 64-arch-VGPR
// budget; LLVM rematerialized the __restrict__ loads at use sites -> 4.7x
// dijk re-fetch (FETCH 4.85 GB). Fix: DMA the f32 tile straight to LDS
// (zero regs held), pre-swizzling the GLOBAL source address so the linear
// LDS write lands XOR-swizzled (conflict-free ds_read_b128 A-frag reads).
// Reduce is deferred one tile so its stores/atomics complete under compute.

typedef float  f32x4  __attribute__((ext_vector_type(4)));
typedef __bf16 bf16x8 __attribute__((ext_vector_type(8)));

// may_alias views for LDS type-punning (R5 lesson)
typedef uint32_t u32a    __attribute__((may_alias));
typedef f32x4    f32x4a  __attribute__((may_alias));
typedef bf16x8   bf16x8a __attribute__((may_alias));
typedef __bf16   bf16a   __attribute__((may_alias));

static constexpr int   N_TRIPLES = 2000000;
static constexpr int   DIM       = 128;
static constexpr int   NSEG      = 100000;
static constexpr int   NBLOCKS   = 768;                       // 3 blocks/CU exactly
static constexpr int   NWAVES    = NBLOCKS * 4;               // 3072
static constexpr int   M_TILES   = N_TRIPLES / 16;            // 125000
static constexpr int   BASE_T    = M_TILES / NWAVES;          // 40
static constexpr int   REM_T     = M_TILES - BASE_T * NWAVES; // 2120
static constexpr float LOG2F_    = 0.6931471805599453f;

#define GLD16(gp_, lp_)                                                        \
  __builtin_amdgcn_global_load_lds(                                            \
      (const __attribute__((address_space(1))) void*)(gp_),                    \
      (__attribute__((address_space(3))) void*)(lp_), 16, 0, 0)

// softplus only (layer-1's -log2 folded into b2'; layer 2 subtracts it)
__device__ __forceinline__ float sp_(float x) {
  float e = __expf(-fabsf(x));
  return fmaxf(x, 0.0f) + __logf(1.0f + e);
}

// Transpose W1,W2 [k][n] f32 -> WT [n][k] bf16 (MFMA B-frags contiguous in k)
__global__ void wt_kernel(const float* __restrict__ W1, const float* __restrict__ W2,
                          __bf16* __restrict__ WT) {
  int t = blockIdx.x * 256 + threadIdx.x;   // 0..16383
  int k = t >> 7;
  int n = t & 127;
  WT[n * 128 + k]         = (__bf16)W1[t];
  WT[16384 + n * 128 + k] = (__bf16)W2[t];
}

// b2'[n] = b2[n] - log2 * sum_k W2[k][n]
__global__ void bias_kernel(const float* __restrict__ W2, const float* __restrict__ b2,
                            float* __restrict__ b2p) {
  int n = threadIdx.x;
  float s = 0.0f;
  #pragma unroll 8
  for (int k = 0; k < 128; ++k) s += W2[k * 128 + n];
  b2p[n] = b2[n] - LOG2F_ * s;
}

__global__ __launch_bounds__(256, 3) void fused_kernel(
    const float* __restrict__ dijk, const int* __restrict__ seg,
    const __bf16* __restrict__ WT,
    const float* __restrict__ b1v, const float* __restrict__ b2p,
    float* __restrict__ out)
{
  // per wave: 8 KB f32 tile (DMA target, swizzled image) + 4 KB h/wijk tile
  __shared__ char lds_all[4 * 12288];   // 48 KB -> 3 blocks/CU

  const int tid  = threadIdx.x;
  const int lane = tid & 63;
  const int wave = tid >> 6;
  const int l15  = lane & 15;
  const int g    = lane >> 4;

  const int wid  = blockIdx.x * 4 + wave;
  const int n_t  = BASE_T + (wid < REM_T ? 1 : 0);
  const int t0   = wid * BASE_T + (wid < REM_T ? wid : REM_T);
  const int row0 = t0 * 16;               // first row of this wave's chunk

  char* ftw = lds_all + wave * 12288;           // f32 tile (swizzled), 8 KB
  char* hb  = lds_all + wave * 12288 + 8192;    // h / wijk tile, 4 KB

  // biases for this lane's 8 column slots (col = nt*16 + l15)
  float bias1[8], bias2[8];
  #pragma unroll
  for (int nt = 0; nt < 8; ++nt) {
    bias1[nt] = b1v[nt * 16 + l15];
    bias2[nt] = b2p[nt * 16 + l15];
  }

  const __bf16* WT1 = WT;
  const __bf16* WT2 = WT + 16384;

  const int srow0 = __builtin_amdgcn_readfirstlane(row0);
  const int* sp = seg + srow0;            // uniform -> scalar loads
  const int first_seg = sp[0];
  const int colb = lane * 2;              // this lane's output column pair
  const int sw   = (l15 & 7) << 4;        // A-read swizzle for this lane's row

  // DMA: instruction i writes LDS linear [i*1024 + lane*16, +16); that byte
  // belongs to (row = 2i + lane/32, b_phys = (lane&31)*16). Source is
  // pre-swizzled: b_log = b_phys ^ ((row&7)<<4)  (involution).
  const char* gchunk = (const char*)dijk + (size_t)row0 * 512;
  const int h5    = lane >> 5;
  const int bphys = (lane & 31) * 16;
  auto issue_dma = [&](int tile) {
    const char* tb = gchunk + (size_t)tile * 8192;
    #pragma unroll
    for (int i = 0; i < 8; ++i) {
      int row  = 2 * i + h5;
      int blog = bphys ^ ((row & 7) << 4);
      GLD16(tb + (size_t)row * 512 + blog, ftw + i * 1024);
    }
  };

  issue_dma(0);

  float a0 = 0.0f, a1 = 0.0f;
  int cur = first_seg;
  uint32_t vprev[16];

  for (int it = 0; it < n_t; ++it) {
    // wait for this tile's DMA (and long-ago stores); then A-frags from LDS
    asm volatile("s_waitcnt vmcnt(0)" ::: "memory");
    bf16x8 afrag[4];
    #pragma unroll
    for (int ks = 0; ks < 4; ++ks) {
      int bl = ks * 128 + g * 32;
      f32x4 lo = *(const f32x4a*)(ftw + l15 * 512 + ((bl)      ^ sw));
      f32x4 hi = *(const f32x4a*)(ftw + l15 * 512 + ((bl + 16) ^ sw));
      bf16x8 t8;
      t8[0] = (__bf16)lo[0]; t8[1] = (__bf16)lo[1]; t8[2] = (__bf16)lo[2]; t8[3] = (__bf16)lo[3];
      t8[4] = (__bf16)hi[0]; t8[5] = (__bf16)hi[1]; t8[6] = (__bf16)hi[2]; t8[7] = (__bf16)hi[3];
      afrag[ks] = t8;
    }
    // all f32 reads done before the DMA may overwrite the buffer
    asm volatile("s_waitcnt lgkmcnt(0)" ::: "memory");
    __builtin_amdgcn_sched_barrier(0);
    if (it + 1 < n_t) issue_dma(it + 1);
    __builtin_amdgcn_sched_barrier(0);

    // deferred reduce of tile it-1 (stores issue here, complete under compute)
    if (it > 0) {
      const int* st = sp + (it - 1) * 16;
      #pragma unroll
      for (int k = 0; k < 16; ++k) {
        int s = st[k];                    // uniform -> scalar load
        if (s != cur) {                   // wave-uniform branch
          if (cur == first_seg) {
            atomicAdd(out + (size_t)cur * DIM + colb,     a0);
            atomicAdd(out + (size_t)cur * DIM + colb + 1, a1);
          } else {
            float2 w2; w2.x = a0; w2.y = a1;
            *(float2*)(out + (size_t)cur * DIM + colb) = w2;
          }
          a0 = 0.0f; a1 = 0.0f; cur = s;
        }
        uint32_t w = vprev[k];
        a0 += __uint_as_float(w << 16);
        a1 += __uint_as_float(w & 0xffff0000u);
      }
    }

    // ---------------- GEMM1: h' = softplus(A @ W1 + b1) ----------------
    f32x4 acc[8];
    #pragma unroll
    for (int nt = 0; nt < 8; ++nt) acc[nt] = (f32x4){0.f, 0.f, 0.f, 0.f};
    #pragma unroll
    for (int ks = 0; ks < 4; ++ks) {
      #pragma unroll
      for (int nt = 0; nt < 8; ++nt) {
        bf16x8 bfrag = *(const bf16x8*)(WT1 + (nt * 16 + l15) * DIM + ks * 32 + g * 8);
        acc[nt] = __builtin_amdgcn_mfma_f32_16x16x32_bf16(afrag[ks], bfrag, acc[nt], 0, 0, 0);
      }
    }
    // softplus + h' -> LDS (bf16, XOR-swizzled). C/D: row=g*4+j, col=nt*16+l15
    #pragma unroll
    for (int nt = 0; nt < 8; ++nt) {
      #pragma unroll
      for (int j = 0; j < 4; ++j) {
        int row = g * 4 + j;
        int col = nt * 16 + l15;
        float hv = sp_(acc[nt][j] + bias1[nt]);
        *(bf16a*)(hb + row * 256 + ((col * 2) ^ ((row & 7) << 4))) = (__bf16)hv;
      }
    }

    // ---------------- GEMM2: w = softplus(h' @ W2 + b2') - log2 ------------
    f32x4 acc2[8];
    #pragma unroll
    for (int nt = 0; nt < 8; ++nt) acc2[nt] = (f32x4){0.f, 0.f, 0.f, 0.f};
    #pragma unroll
    for (int ks = 0; ks < 4; ++ks) {
      bf16x8 hf = *(const bf16x8a*)(hb + l15 * 256 + ((ks * 64 + g * 16) ^ ((l15 & 7) << 4)));
      #pragma unroll
      for (int nt = 0; nt < 8; ++nt) {
        bf16x8 bfrag = *(const bf16x8*)(WT2 + (nt * 16 + l15) * DIM + ks * 32 + g * 8);
        acc2[nt] = __builtin_amdgcn_mfma_f32_16x16x32_bf16(hf, bfrag, acc2[nt], 0, 0, 0);
      }
    }
    // softplus + wijk -> same LDS tile (in-order DS pipe; reads above done)
    #pragma unroll
    for (int nt = 0; nt < 8; ++nt) {
      #pragma unroll
      for (int j = 0; j < 4; ++j) {
        int row = g * 4 + j;
        int col = nt * 16 + l15;
        float wv = sp_(acc2[nt][j] + bias2[nt]) - LOG2F_;
        *(bf16a*)(hb + row * 256 + ((col * 2) ^ ((row & 7) << 4))) = (__bf16)wv;
      }
    }

    // stage this tile's wijk column-pair for next iteration's deferred reduce
    #pragma unroll
    for (int k = 0; k < 16; ++k)
      vprev[k] = *(const u32a*)(hb + k * 256 + ((colb * 2) ^ ((k & 7) << 4)));
  }

  // epilogue: reduce the last tile, then final flush (may cross chunks)
  {
    const int* st = sp + (n_t - 1) * 16;
    #pragma unroll
    for (int k = 0; k < 16; ++k) {
      int s = st[k];
      if (s != cur) {
        if (cur == first_seg) {
          atomicAdd(out + (size_t)cur * DIM + colb,     a0);
          atomicAdd(out + (size_t)cur * DIM + colb + 1, a1);
        } else {
          float2 w2; w2.x = a0; w2.y = a1;
          *(float2*)(out + (size_t)cur * DIM + colb) = w2;
        }
        a0 = 0.0f; a1 = 0.0f; cur = s;
      }
      uint32_t w = vprev[k];
      a0 += __uint_as_float(w << 16);
      a1 += __uint_as_float(w & 0xffff0000u);
    }
    atomicAdd(out + (size_t)cur * DIM + colb,     a0);
    atomicAdd(out + (size_t)cur * DIM + colb + 1, a1);
  }
}

extern "C" void kernel_launch(void* const* d_in, const int* in_sizes, int n_in,
                              void* d_out, int out_size, void* d_ws, size_t ws_size,
                              hipStream_t stream) {
  const float* dijk = (const float*)d_in[0];
  const int*   seg  = (const int*)d_in[1];
  const float* W1   = (const float*)d_in[2];
  const float* b1   = (const float*)d_in[3];
  const float* W2   = (const float*)d_in[4];
  const float* b2   = (const float*)d_in[5];
  float* out = (float*)d_out;

  float*  b2p = (float*)d_ws;                       // 128 f32
  __bf16* WT  = (__bf16*)((char*)d_ws + 1024);      // 2 * 128*128 bf16 = 64 KB

  // empty segments must be exactly 0; interior stores overwrite, boundary
  // atomics accumulate; memset re-zeroes every replay (graph-safe).
  hipMemsetAsync(out, 0, (size_t)NSEG * DIM * sizeof(float), stream);

  wt_kernel<<<64, 256, 0, stream>>>(W1, W2, WT);
  bias_kernel<<<1, 128, 0, stream>>>(W2, b2, b2p);

  fused_kernel<<<NBLOCKS, 256, 0, stream>>>(dijk, seg, WT, b1, b2p, out);
}

// Round 8
// 1092.944 us; speedup vs baseline: 1.7699x; 1.3427x over previous
//
#include <hip/hip_runtime.h>
#include <hip/hip_bf16.h>
#include <cstdint>
#include <cstddef>

// CFnetFilter: w_ij = segment_sum(ssp(ssp(dijk@W1+b1)@W2+b2), seg_j)
//
// R8 = R1 (best known, 869us) with ONLY the reduce changed: ownership-based
// parallel reduce. All 4 waves reduce after one barrier; wave w owns the
// segments STARTING in rows [32w,32w+32) and walks them to their end (possibly
// past the span). Interior segments -> exclusive float2 stores; only the
// block-first segment and segments touching row 127 -> atomicAdd.
// Atomics: 16.8M -> ~4M with NO serial tail (R4 confounded atomic-reduction
// with a wave0-only serial reduce; this is the clean experiment).

typedef float  f32x4  __attribute__((ext_vector_type(4)));
typedef __bf16 bf16x8 __attribute__((ext_vector_type(8)));

// may_alias views for LDS type-punning (R5 lesson)
typedef uint32_t u32a    __attribute__((may_alias));
typedef bf16x8   bf16x8a __attribute__((may_alias));
typedef __bf16   bf16a   __attribute__((may_alias));

static constexpr int   N_TRIPLES = 2000000;
static constexpr int   DIM       = 128;
static constexpr int   NSEG      = 100000;
static constexpr int   ROWS      = 128;     // rows per block (2e6 / 128 exact)
static constexpr float LOG2F_    = 0.6931471805599453f;

// softplus only (layer-1's -log2 folded into b2'; layer 2 subtracts it)
__device__ __forceinline__ float sp_(float x) {
  float e = __expf(-fabsf(x));
  return fmaxf(x, 0.0f) + __logf(1.0f + e);
}

// Transpose W1,W2 [k][n] f32 -> WT [n][k] bf16 (MFMA B-frags contiguous in k)
__global__ void wt_kernel(const float* __restrict__ W1, const float* __restrict__ W2,
                          __bf16* __restrict__ WT) {
  int t = blockIdx.x * 256 + threadIdx.x;   // 0..16383
  int k = t >> 7;
  int n = t & 127;
  WT[n * 128 + k]         = (__bf16)W1[t];
  WT[16384 + n * 128 + k] = (__bf16)W2[t];
}

// b2'[n] = b2[n] - log2 * sum_k W2[k][n]  (folds layer-1's -log2 into bias 2)
__global__ void bias_kernel(const float* __restrict__ W2, const float* __restrict__ b2,
                            float* __restrict__ b2p) {
  int n = threadIdx.x;
  float s = 0.0f;
  #pragma unroll 8
  for (int k = 0; k < 128; ++k) s += W2[k * 128 + n];
  b2p[n] = b2[n] - LOG2F_ * s;
}

__global__ __launch_bounds__(256, 4) void fused_kernel(
    const float* __restrict__ dijk, const int* __restrict__ seg,
    const __bf16* __restrict__ WT,
    const float* __restrict__ b1v, const float* __restrict__ b2p,
    float* __restrict__ out)
{
  __shared__ __bf16 hbuf[ROWS * DIM];   // exactly 32 KB; h then wijk, swizzled

  const int tid  = threadIdx.x;
  const int lane = tid & 63;
  const int wave = tid >> 6;
  const int l15  = lane & 15;
  const int g    = lane >> 4;           // quarter-wave group (k-group for frags)
  const int r0   = blockIdx.x * ROWS;
  const int wrow = wave * 32;           // this wave's first row within the block

  // biases for this lane's 8 column slots (col = nt*16 + l15)
  float bias1[8], bias2[8];
  #pragma unroll
  for (int nt = 0; nt < 8; ++nt) {
    bias1[nt] = b1v[nt * 16 + l15];
    bias2[nt] = b2p[nt * 16 + l15];
  }

  char* hb = (char*)hbuf;

  // ---------------- GEMM1: h' = softplus(dijk @ W1 + b1) ----------------
  f32x4 acc[2][8] = {};
  {
    const __bf16* WT1 = WT;
    #pragma unroll
    for (int ks = 0; ks < 4; ++ks) {
      bf16x8 afrag[2];
      #pragma unroll
      for (int mt = 0; mt < 2; ++mt) {
        const float* p = dijk + (size_t)(r0 + wrow + mt * 16 + l15) * DIM + ks * 32 + g * 8;
        f32x4 v0 = *(const f32x4*)p;
        f32x4 v1 = *(const f32x4*)(p + 4);
        bf16x8 t8;
        t8[0] = (__bf16)v0[0]; t8[1] = (__bf16)v0[1]; t8[2] = (__bf16)v0[2]; t8[3] = (__bf16)v0[3];
        t8[4] = (__bf16)v1[0]; t8[5] = (__bf16)v1[1]; t8[6] = (__bf16)v1[2]; t8[7] = (__bf16)v1[3];
        afrag[mt] = t8;
      }
      #pragma unroll
      for (int nt = 0; nt < 8; ++nt) {
        bf16x8 bfrag = *(const bf16x8*)(WT1 + (nt * 16 + l15) * DIM + ks * 32 + g * 8);
        acc[0][nt] = __builtin_amdgcn_mfma_f32_16x16x32_bf16(afrag[0], bfrag, acc[0][nt], 0, 0, 0);
        acc[1][nt] = __builtin_amdgcn_mfma_f32_16x16x32_bf16(afrag[1], bfrag, acc[1][nt], 0, 0, 0);
      }
    }
  }

  // bias + softplus, h' -> LDS (bf16, XOR-swizzled). Own-wave rows only.
  #pragma unroll
  for (int mt = 0; mt < 2; ++mt) {
    #pragma unroll
    for (int nt = 0; nt < 8; ++nt) {
      #pragma unroll
      for (int j = 0; j < 4; ++j) {
        int row = wrow + mt * 16 + g * 4 + j;   // C/D: row=(lane>>4)*4+j
        int col = nt * 16 + l15;                //      col=lane&15
        float hv = sp_(acc[mt][nt][j] + bias1[nt]);
        *(bf16a*)(hb + row * 256 + ((col * 2) ^ ((row & 7) << 4))) = (__bf16)hv;
      }
    }
  }

  // ---------------- GEMM2: w = softplus(h' @ W2 + b2') - log2 ----------------
  f32x4 acc2[2][8] = {};
  {
    const __bf16* WT2 = WT + 16384;
    #pragma unroll
    for (int ks = 0; ks < 4; ++ks) {
      bf16x8 afrag[2];
      #pragma unroll
      for (int mt = 0; mt < 2; ++mt) {
        int row = wrow + mt * 16 + l15;         // A: row=lane&15
        int kb  = (ks * 64 + g * 16) ^ ((row & 7) << 4);
        afrag[mt] = *(const bf16x8a*)(hb + row * 256 + kb);
      }
      #pragma unroll
      for (int nt = 0; nt < 8; ++nt) {
        bf16x8 bfrag = *(const bf16x8*)(WT2 + (nt * 16 + l15) * DIM + ks * 32 + g * 8);
        acc2[0][nt] = __builtin_amdgcn_mfma_f32_16x16x32_bf16(afrag[0], bfrag, acc2[0][nt], 0, 0, 0);
        acc2[1][nt] = __builtin_amdgcn_mfma_f32_16x16x32_bf16(afrag[1], bfrag, acc2[1][nt], 0, 0, 0);
      }
    }
  }

  // bias + ssp, wijk -> same LDS rows (own-wave; prior reads complete in-order)
  #pragma unroll
  for (int mt = 0; mt < 2; ++mt) {
    #pragma unroll
    for (int nt = 0; nt < 8; ++nt) {
      #pragma unroll
      for (int j = 0; j < 4; ++j) {
        int row = wrow + mt * 16 + g * 4 + j;
        int col = nt * 16 + l15;
        float wv = sp_(acc2[mt][nt][j] + bias2[nt]) - LOG2F_;
        *(bf16a*)(hb + row * 256 + ((col * 2) ^ ((row & 7) << 4))) = (__bf16)wv;
      }
    }
  }

  __syncthreads();   // all 128 wijk rows visible to all waves

  // ---------------- ownership-based parallel segmented reduce ----------------
  // Wave w owns segments STARTING in rows [32w, 32w+32); it walks each owned
  // segment to its end (possibly past the span, up to row 127). Lane owns
  // cols {2*lane, 2*lane+1}. Segment ids are wave-uniform -> scalar loads +
  // uniform branches. Interior segments (not block-first, end before row 128)
  // have exactly one writer in the whole grid -> plain float2 store.
  {
    const int colb = lane * 2;
    const int* sp = seg + r0;            // uniform -> scalar loads
    const int span_lo = wave * 32;
    const int span_hi = span_lo + 32;
    const int bfirst = sp[0];

    int r = span_lo;
    if (wave > 0) {
      // skip rows whose segment started before our span (owned by earlier wave)
      const int prev = sp[span_lo - 1];
      while (r < span_hi && sp[r] == prev) ++r;
    }

    if (r < span_hi) {
      float a0 = 0.0f, a1 = 0.0f;
      int cur = sp[r];
      uint32_t vcur = *(const u32a*)(hb + r * 256 + ((colb * 2) ^ ((r & 7) << 4)));
      while (true) {
        a0 += __uint_as_float(vcur << 16);          // bf16 lo -> f32
        a1 += __uint_as_float(vcur & 0xffff0000u);  // bf16 hi -> f32
        ++r;
        if (r == ROWS) {
          // segment touches block end -> may continue in next block -> atomic
          atomicAdd(out + (size_t)cur * DIM + colb,     a0);
          atomicAdd(out + (size_t)cur * DIM + colb + 1, a1);
          break;
        }
        int s = sp[r];
        vcur = *(const u32a*)(hb + r * 256 + ((colb * 2) ^ ((r & 7) << 4)));
        if (s != cur) {
          // segment ended inside the block
          if (cur == bfirst) {           // may extend into previous block
            atomicAdd(out + (size_t)cur * DIM + colb,     a0);
            atomicAdd(out + (size_t)cur * DIM + colb + 1, a1);
          } else {                       // interior: exclusive writer -> store
            float2 w2; w2.x = a0; w2.y = a1;
            *(float2*)(out + (size_t)cur * DIM + colb) = w2;
          }
          if (r >= span_hi) break;       // next segment starts beyond our span
          cur = s; a0 = 0.0f; a1 = 0.0f;
        }
      }
    }
  }
}

extern "C" void kernel_launch(void* const* d_in, const int* in_sizes, int n_in,
                              void* d_out, int out_size, void* d_ws, size_t ws_size,
                              hipStream_t stream) {
  const float* dijk = (const float*)d_in[0];
  const int*   seg  = (const int*)d_in[1];
  const float* W1   = (const float*)d_in[2];
  const float* b1   = (const float*)d_in[3];
  const float* W2   = (const float*)d_in[4];
  const float* b2   = (const float*)d_in[5];
  float* out = (float*)d_out;

  float*  b2p = (float*)d_ws;                       // 128 f32
  __bf16* WT  = (__bf16*)((char*)d_ws + 1024);      // 2 * 128*128 bf16 = 64 KB

  // empty segments must be exactly 0; interior stores overwrite, boundary
  // atomics accumulate; memset re-zeroes every replay (graph-safe).
  hipMemsetAsync(out, 0, (size_t)NSEG * DIM * sizeof(float), stream);

  wt_kernel<<<64, 256, 0, stream>>>(W1, W2, WT);
  bias_kernel<<<1, 128, 0, stream>>>(W2, b2, b2p);

  fused_kernel<<<N_TRIPLES / ROWS, 256, 0, stream>>>(dijk, seg, WT, b1, b2p, out);
}

// Round 9
// 576.371 us; speedup vs baseline: 3.3561x; 1.8963x over previous
//
#include <hip/hip_runtime.h>
#include <hip/hip_bf16.h>
#include <cstdint>
#include <cstddef>

// CFnetFilter: w_ij = segment_sum(ssp(ssp(dijk@W1+b1)@W2+b2), seg_j)
//
// R9: column-split waves. R1 ledger audit: every wave re-read ALL of WT
// (64 KB) per 32 rows -> 4 GB of B-frag traffic through a thrashed L1 ->
// L2-latency-bound MFMA chains. Here a 512-thread block (8 waves) owns 128
// rows; wave w owns cols [16w,16w+16) -> only 8 B-frag loads per wave TOTAL
// (kept in 16 VGPRs), WT traffic 4 GB -> 1 GB. dijk staged once per block
// into a swizzled bf16 LDS A-tile (cooperative, coalesced). h in LDS
// (full-width, shared); wijk overwrites the A-tile. Reduce = R1's proven
// constant-trip serial form (compiler pipelines it), 32 rows per thread.
// LDS 64 KB -> 2 blocks/CU = 16 waves/CU (same occupancy as R1).

typedef float  f32x4  __attribute__((ext_vector_type(4)));
typedef __bf16 bf16x8 __attribute__((ext_vector_type(8)));

// may_alias views for LDS type-punning (R5 lesson)
typedef uint16_t u16a    __attribute__((may_alias));
typedef bf16x8   bf16x8a __attribute__((may_alias));
typedef __bf16   bf16a   __attribute__((may_alias));

static constexpr int   N_TRIPLES = 2000000;
static constexpr int   DIM       = 128;
static constexpr int   NSEG      = 100000;
static constexpr int   ROWS      = 128;     // rows per block (2e6 / 128 exact)
static constexpr float LOG2F_    = 0.6931471805599453f;

// softplus only (layer-1's -log2 folded into b2'; layer 2 subtracts it)
__device__ __forceinline__ float sp_(float x) {
  float e = __expf(-fabsf(x));
  return fmaxf(x, 0.0f) + __logf(1.0f + e);
}

// Transpose W1,W2 [k][n] f32 -> WT [n][k] bf16 (MFMA B-frags contiguous in k)
__global__ void wt_kernel(const float* __restrict__ W1, const float* __restrict__ W2,
                          __bf16* __restrict__ WT) {
  int t = blockIdx.x * 256 + threadIdx.x;   // 0..16383
  int k = t >> 7;
  int n = t & 127;
  WT[n * 128 + k]         = (__bf16)W1[t];
  WT[16384 + n * 128 + k] = (__bf16)W2[t];
}

// b2'[n] = b2[n] - log2 * sum_k W2[k][n]  (folds layer-1's -log2 into bias 2)
__global__ void bias_kernel(const float* __restrict__ W2, const float* __restrict__ b2,
                            float* __restrict__ b2p) {
  int n = threadIdx.x;
  float s = 0.0f;
  #pragma unroll 8
  for (int k = 0; k < 128; ++k) s += W2[k * 128 + n];
  b2p[n] = b2[n] - LOG2F_ * s;
}

__global__ __launch_bounds__(512, 4) void fused_kernel(
    const float* __restrict__ dijk, const int* __restrict__ seg,
    const __bf16* __restrict__ WT,
    const float* __restrict__ b1v, const float* __restrict__ b2p,
    float* __restrict__ out)
{
  __shared__ __bf16 abuf[ROWS * DIM];   // 32 KB: bf16 A-tile, then wijk
  __shared__ __bf16 hbuf[ROWS * DIM];   // 32 KB: h' (full width, shared)

  const int tid  = threadIdx.x;         // 0..511
  const int lane = tid & 63;
  const int wave = tid >> 6;            // 0..7 -> col slice [16w, 16w+16)
  const int l15  = lane & 15;
  const int g    = lane >> 4;           // k-group
  const int r0   = blockIdx.x * ROWS;

  char* ab = (char*)abuf;
  char* hb = (char*)hbuf;

  // ---- stage A: dijk rows -> bf16 LDS tile (swizzled), cooperative ----
  // thread t: row = t>>2, quarter q = t&3 (32 f32). Coalesced 128 B/thread.
  {
    int row = tid >> 2, q = tid & 3;
    const float* src = dijk + (size_t)(r0 + row) * DIM + q * 32;
    char* dst = ab + row * 256;
    int swz = (row & 7) << 4;
    #pragma unroll
    for (int u = 0; u < 4; ++u) {
      f32x4 v0 = *(const f32x4*)(src + u * 8);
      f32x4 v1 = *(const f32x4*)(src + u * 8 + 4);
      bf16x8 t8;
      t8[0] = (__bf16)v0[0]; t8[1] = (__bf16)v0[1]; t8[2] = (__bf16)v0[2]; t8[3] = (__bf16)v0[3];
      t8[4] = (__bf16)v1[0]; t8[5] = (__bf16)v1[1]; t8[6] = (__bf16)v1[2]; t8[7] = (__bf16)v1[3];
      *(bf16x8a*)(dst + ((q * 64 + u * 16) ^ swz)) = t8;
    }
  }

  const int colw = wave * 16 + l15;       // this lane's output column
  const float bias1 = b1v[colw];
  const float bias2 = b2p[colw];

  __syncthreads();   // A-tile complete

  // ---------------- GEMM1: h' = softplus(A @ W1 + b1), cols [16w,16w+16) ----
  {
    bf16x8 bf1[4];
    #pragma unroll
    for (int ks = 0; ks < 4; ++ks)
      bf1[ks] = *(const bf16x8*)(WT + colw * 128 + ks * 32 + g * 8);

    f32x4 acc[8];
    #pragma unroll
    for (int mt = 0; mt < 8; ++mt) acc[mt] = (f32x4){0.f, 0.f, 0.f, 0.f};
    #pragma unroll
    for (int mt = 0; mt < 8; ++mt) {
      int row = mt * 16 + l15;
      int swz = (row & 7) << 4;
      #pragma unroll
      for (int ks = 0; ks < 4; ++ks) {
        bf16x8 a = *(const bf16x8a*)(ab + row * 256 + ((ks * 64 + g * 16) ^ swz));
        acc[mt] = __builtin_amdgcn_mfma_f32_16x16x32_bf16(a, bf1[ks], acc[mt], 0, 0, 0);
      }
    }
    // softplus + h' -> hbuf (C/D: row = mt*16 + g*4 + j, col = colw)
    #pragma unroll
    for (int mt = 0; mt < 8; ++mt) {
      #pragma unroll
      for (int j = 0; j < 4; ++j) {
        int row = mt * 16 + g * 4 + j;
        float hv = sp_(acc[mt][j] + bias1);
        *(bf16a*)(hb + row * 256 + ((colw * 2) ^ ((row & 7) << 4))) = (__bf16)hv;
      }
    }
  }

  __syncthreads();   // h' complete (and all A-reads done -> abuf reusable)

  // ---------------- GEMM2: w = softplus(h' @ W2 + b2') - log2 --------------
  {
    bf16x8 bf2[4];
    #pragma unroll
    for (int ks = 0; ks < 4; ++ks)
      bf2[ks] = *(const bf16x8*)(WT + 16384 + colw * 128 + ks * 32 + g * 8);

    f32x4 acc2[8];
    #pragma unroll
    for (int mt = 0; mt < 8; ++mt) acc2[mt] = (f32x4){0.f, 0.f, 0.f, 0.f};
    #pragma unroll
    for (int mt = 0; mt < 8; ++mt) {
      int row = mt * 16 + l15;
      int swz = (row & 7) << 4;
      #pragma unroll
      for (int ks = 0; ks < 4; ++ks) {
        bf16x8 a = *(const bf16x8a*)(hb + row * 256 + ((ks * 64 + g * 16) ^ swz));
        acc2[mt] = __builtin_amdgcn_mfma_f32_16x16x32_bf16(a, bf2[ks], acc2[mt], 0, 0, 0);
      }
    }
    // softplus + wijk -> abuf (free after barrier #2)
    #pragma unroll
    for (int mt = 0; mt < 8; ++mt) {
      #pragma unroll
      for (int j = 0; j < 4; ++j) {
        int row = mt * 16 + g * 4 + j;
        float wv = sp_(acc2[mt][j] + bias2) - LOG2F_;
        *(bf16a*)(ab + row * 256 + ((colw * 2) ^ ((row & 7) << 4))) = (__bf16)wv;
      }
    }
  }

  __syncthreads();   // wijk complete, visible to all

  // ---------------- segmented reduce (R1's proven constant-trip form) ------
  // thread: col = tid&127, quarter hh = tid>>7 -> rows [hh*32, hh*32+32).
  // Segment ids wave-uniform -> scalar loads + uniform branch; flush always
  // atomic (atomics are fire-and-forget; R3/R8 showed count is non-binding).
  {
    const int col = tid & 127;
    const int hh  = tid >> 7;           // 0..3
    const int rbeg = hh * 32;
    const int* sp = seg + r0;
    float accum = 0.0f;
    int cur = sp[rbeg];
    #pragma unroll
    for (int i = 0; i < 32; ++i) {
      int row = rbeg + i;
      int s = sp[row];
      if (s != cur) {
        atomicAdd(out + (size_t)cur * DIM + col, accum);
        accum = 0.0f; cur = s;
      }
      uint16_t u = *(const u16a*)(ab + row * 256 + ((col * 2) ^ ((row & 7) << 4)));
      accum += __uint_as_float(((uint32_t)u) << 16);
    }
    atomicAdd(out + (size_t)cur * DIM + col, accum);
  }
}

extern "C" void kernel_launch(void* const* d_in, const int* in_sizes, int n_in,
                              void* d_out, int out_size, void* d_ws, size_t ws_size,
                              hipStream_t stream) {
  const float* dijk = (const float*)d_in[0];
  const int*   seg  = (const int*)d_in[1];
  const float* W1   = (const float*)d_in[2];
  const float* b1   = (const float*)d_in[3];
  const float* W2   = (const float*)d_in[4];
  const float* b2   = (const float*)d_in[5];
  float* out = (float*)d_out;

  float*  b2p = (float*)d_ws;                       // 128 f32
  __bf16* WT  = (__bf16*)((char*)d_ws + 1024);      // 2 * 128*128 bf16 = 64 KB

  // empty segments must be exactly 0; memset re-zeroes every replay
  hipMemsetAsync(out, 0, (size_t)NSEG * DIM * sizeof(float), stream);

  wt_kernel<<<64, 256, 0, stream>>>(W1, W2, WT);
  bias_kernel<<<1, 128, 0, stream>>>(W2, b2, b2p);

  fused_kernel<<<N_TRIPLES / ROWS, 512, 0, stream>>>(dijk, seg, WT, b1, b2p, out);
}

// Round 10
// 517.182 us; speedup vs baseline: 3.7402x; 1.1144x over previous
//
#include <hip/hip_runtime.h>
#include <hip/hip_bf16.h>
#include <cstdint>
#include <cstddef>

// CFnetFilter: w_ij = segment_sum(ssp(ssp(dijk@W1+b1)@W2+b2), seg_j)
//
// R10 = R9 (column-split waves, 576us) + single 32KB LDS buffer.
// R9 post-mortem: VALU 62.7% top pipe, occupancy capped at 45.5% by 64KB LDS
// (2 blocks/CU). A-tile and h-tile are never simultaneously live -> one
// buffer, phase-separated by barriers: stage A -> GEMM1(reads A) -> BAR ->
// h' overwrites A -> BAR -> GEMM2(reads h) -> BAR -> wijk overwrites h ->
// BAR -> reduce. LDS 32KB -> 3 blocks/CU (24 waves, 75%) at <=85 regs
// (__launch_bounds__(512,6); currently ~52 VGPR + 32 AGPR = 84).
// acc registers carry h across the barrier (they're AGPRs regardless).
// Reduce reverted to R1's paired-column u32 form (R9's scalar u16 reads
// were a bank-conflict suspect; u32 pairs are conflict-free).

typedef float  f32x4  __attribute__((ext_vector_type(4)));
typedef __bf16 bf16x8 __attribute__((ext_vector_type(8)));

// may_alias views for LDS type-punning (R5 lesson)
typedef uint32_t u32a    __attribute__((may_alias));
typedef bf16x8   bf16x8a __attribute__((may_alias));
typedef __bf16   bf16a   __attribute__((may_alias));

static constexpr int   N_TRIPLES = 2000000;
static constexpr int   DIM       = 128;
static constexpr int   NSEG      = 100000;
static constexpr int   ROWS      = 128;     // rows per block (2e6 / 128 exact)
static constexpr float LOG2F_    = 0.6931471805599453f;

// softplus only (layer-1's -log2 folded into b2'; layer 2 subtracts it)
__device__ __forceinline__ float sp_(float x) {
  float e = __expf(-fabsf(x));
  return fmaxf(x, 0.0f) + __logf(1.0f + e);
}

// Transpose W1,W2 [k][n] f32 -> WT [n][k] bf16 (MFMA B-frags contiguous in k)
__global__ void wt_kernel(const float* __restrict__ W1, const float* __restrict__ W2,
                          __bf16* __restrict__ WT) {
  int t = blockIdx.x * 256 + threadIdx.x;   // 0..16383
  int k = t >> 7;
  int n = t & 127;
  WT[n * 128 + k]         = (__bf16)W1[t];
  WT[16384 + n * 128 + k] = (__bf16)W2[t];
}

// b2'[n] = b2[n] - log2 * sum_k W2[k][n]  (folds layer-1's -log2 into bias 2)
__global__ void bias_kernel(const float* __restrict__ W2, const float* __restrict__ b2,
                            float* __restrict__ b2p) {
  int n = threadIdx.x;
  float s = 0.0f;
  #pragma unroll 8
  for (int k = 0; k < 128; ++k) s += W2[k * 128 + n];
  b2p[n] = b2[n] - LOG2F_ * s;
}

__global__ __launch_bounds__(512, 6) void fused_kernel(
    const float* __restrict__ dijk, const int* __restrict__ seg,
    const __bf16* __restrict__ WT,
    const float* __restrict__ b1v, const float* __restrict__ b2p,
    float* __restrict__ out)
{
  __shared__ __bf16 tile[ROWS * DIM];   // 32 KB: A, then h', then wijk

  const int tid  = threadIdx.x;         // 0..511
  const int lane = tid & 63;
  const int wave = tid >> 6;            // 0..7 -> col slice [16w, 16w+16)
  const int l15  = lane & 15;
  const int g    = lane >> 4;           // k-group
  const int r0   = blockIdx.x * ROWS;

  char* tb = (char*)tile;

  // ---- phase 0: stage A = bf16(dijk rows) -> LDS (swizzled), cooperative ----
  // thread t: row = t>>2, quarter q = t&3 (32 f32). Coalesced 128 B/thread.
  {
    int row = tid >> 2, q = tid & 3;
    const float* src = dijk + (size_t)(r0 + row) * DIM + q * 32;
    char* dst = tb + row * 256;
    int swz = (row & 7) << 4;
    #pragma unroll
    for (int u = 0; u < 4; ++u) {
      f32x4 v0 = *(const f32x4*)(src + u * 8);
      f32x4 v1 = *(const f32x4*)(src + u * 8 + 4);
      bf16x8 t8;
      t8[0] = (__bf16)v0[0]; t8[1] = (__bf16)v0[1]; t8[2] = (__bf16)v0[2]; t8[3] = (__bf16)v0[3];
      t8[4] = (__bf16)v1[0]; t8[5] = (__bf16)v1[1]; t8[6] = (__bf16)v1[2]; t8[7] = (__bf16)v1[3];
      *(bf16x8a*)(dst + ((q * 64 + u * 16) ^ swz)) = t8;
    }
  }

  const int colw = wave * 16 + l15;       // this lane's output column
  const float bias1 = b1v[colw];
  const float bias2 = b2p[colw];

  __syncthreads();   // [1] A-tile complete

  // ---- phase 1: GEMM1 (reads A), acc kept in AGPRs across the barrier ----
  f32x4 acc[8];
  {
    bf16x8 bf1[4];
    #pragma unroll
    for (int ks = 0; ks < 4; ++ks)
      bf1[ks] = *(const bf16x8*)(WT + colw * 128 + ks * 32 + g * 8);

    #pragma unroll
    for (int mt = 0; mt < 8; ++mt) acc[mt] = (f32x4){0.f, 0.f, 0.f, 0.f};
    #pragma unroll
    for (int mt = 0; mt < 8; ++mt) {
      int row = mt * 16 + l15;
      int swz = (row & 7) << 4;
      #pragma unroll
      for (int ks = 0; ks < 4; ++ks) {
        bf16x8 a = *(const bf16x8a*)(tb + row * 256 + ((ks * 64 + g * 16) ^ swz));
        acc[mt] = __builtin_amdgcn_mfma_f32_16x16x32_bf16(a, bf1[ks], acc[mt], 0, 0, 0);
      }
    }
  }

  __syncthreads();   // [2] all A-reads done -> tile reusable for h'

  // ---- phase 2: softplus + h' -> tile (C/D: row = mt*16 + g*4 + j) ----
  #pragma unroll
  for (int mt = 0; mt < 8; ++mt) {
    #pragma unroll
    for (int j = 0; j < 4; ++j) {
      int row = mt * 16 + g * 4 + j;
      float hv = sp_(acc[mt][j] + bias1);
      *(bf16a*)(tb + row * 256 + ((colw * 2) ^ ((row & 7) << 4))) = (__bf16)hv;
    }
  }

  __syncthreads();   // [3] h' complete

  // ---- phase 3: GEMM2 (reads h') ----
  f32x4 acc2[8];
  {
    bf16x8 bf2[4];
    #pragma unroll
    for (int ks = 0; ks < 4; ++ks)
      bf2[ks] = *(const bf16x8*)(WT + 16384 + colw * 128 + ks * 32 + g * 8);

    #pragma unroll
    for (int mt = 0; mt < 8; ++mt) acc2[mt] = (f32x4){0.f, 0.f, 0.f, 0.f};
    #pragma unroll
    for (int mt = 0; mt < 8; ++mt) {
      int row = mt * 16 + l15;
      int swz = (row & 7) << 4;
      #pragma unroll
      for (int ks = 0; ks < 4; ++ks) {
        bf16x8 a = *(const bf16x8a*)(tb + row * 256 + ((ks * 64 + g * 16) ^ swz));
        acc2[mt] = __builtin_amdgcn_mfma_f32_16x16x32_bf16(a, bf2[ks], acc2[mt], 0, 0, 0);
      }
    }
  }

  __syncthreads();   // [4] all h-reads done -> tile reusable for wijk

  // ---- phase 4: softplus + wijk -> tile ----
  #pragma unroll
  for (int mt = 0; mt < 8; ++mt) {
    #pragma unroll
    for (int j = 0; j < 4; ++j) {
      int row = mt * 16 + g * 4 + j;
      float wv = sp_(acc2[mt][j] + bias2) - LOG2F_;
      *(bf16a*)(tb + row * 256 + ((colw * 2) ^ ((row & 7) << 4))) = (__bf16)wv;
    }
  }

  __syncthreads();   // [5] wijk complete, visible to all

  // ---- phase 5: segmented reduce (R1's paired-column u32 form) ----
  // thread: col pair colb = (tid&63)*2, row group hh = tid>>6 -> 16 rows.
  // Segment ids uniform in each 64-thread group -> scalar loads + uniform
  // branch. Flushes atomic (fire-and-forget; L2 coalesces same-line RMWs).
  {
    const int colb = (tid & 63) * 2;
    const int hh   = tid >> 6;           // 0..7
    const int rbeg = hh * 16;
    const int* sp = seg + r0;
    float a0 = 0.0f, a1 = 0.0f;
    int cur = sp[rbeg];
    #pragma unroll
    for (int i = 0; i < 16; ++i) {
      int row = rbeg + i;
      int s = sp[row];
      if (s != cur) {
        atomicAdd(out + (size_t)cur * DIM + colb,     a0);
        atomicAdd(out + (size_t)cur * DIM + colb + 1, a1);
        a0 = 0.0f; a1 = 0.0f; cur = s;
      }
      uint32_t w = *(const u32a*)(tb + row * 256 + ((colb * 2) ^ ((row & 7) << 4)));
      a0 += __uint_as_float(w << 16);          // bf16 lo -> f32
      a1 += __uint_as_float(w & 0xffff0000u);  // bf16 hi -> f32
    }
    atomicAdd(out + (size_t)cur * DIM + colb,     a0);
    atomicAdd(out + (size_t)cur * DIM + colb + 1, a1);
  }
}

extern "C" void kernel_launch(void* const* d_in, const int* in_sizes, int n_in,
                              void* d_out, int out_size, void* d_ws, size_t ws_size,
                              hipStream_t stream) {
  const float* dijk = (const float*)d_in[0];
  const int*   seg  = (const int*)d_in[1];
  const float* W1   = (const float*)d_in[2];
  const float* b1   = (const float*)d_in[3];
  const float* W2   = (const float*)d_in[4];
  const float* b2   = (const float*)d_in[5];
  float* out = (float*)d_out;

  float*  b2p = (float*)d_ws;                       // 128 f32
  __bf16* WT  = (__bf16*)((char*)d_ws + 1024);      // 2 * 128*128 bf16 = 64 KB

  // empty segments must be exactly 0; memset re-zeroes every replay
  hipMemsetAsync(out, 0, (size_t)NSEG * DIM * sizeof(float), stream);

  wt_kernel<<<64, 256, 0, stream>>>(W1, W2, WT);
  bias_kernel<<<1, 128, 0, stream>>>(W2, b2, b2p);

  fused_kernel<<<N_TRIPLES / ROWS, 512, 0, stream>>>(dijk, seg, WT, b1, b2p, out);
}

// Round 12
// 422.742 us; speedup vs baseline: 4.5757x; 1.2234x over previous
//
#include <hip/hip_runtime.h>
#include <hip/hip_bf16.h>
#include <cstdint>
#include <cstddef>

// CFnetFilter: w_ij = segment_sum(ssp(ssp(dijk@W1+b1)@W2+b2), seg_j)
//
// R12 = R11 with the compile fix: __exp2f/__log2f collide with glibc math.h
// macros on the host pass -> use __builtin_amdgcn_exp2f / __builtin_amdgcn_logf
// (v_exp_f32 IS 2^x, v_log_f32 IS log2 on AMD).
//
// R11 content: R10 (column-split waves, single 32KB LDS tile, ~500us fused)
// + VALU instruction diet:
//  (a) Base-2 softplus with scales folded into weights/biases:
//      W1' = W1*log2e, b1' = b1*log2e  -> y1 = A@W1' + b1'
//      u1  = max(y1,0) + log2(1+exp2(-|y1|))   [= softplus(x1)/ln2, stored bf16]
//      W2 UNCHANGED (ln2*log2e = 1), b2'' = (b2 - ln2*colsum(W2))*log2e
//      u2  = same form;  w = fma(u2, ln2, -ln2)
//      exp2(-abs y) is ONE v_exp via input modifiers -> 5 insts (2 trans) vs 8.
//  (b) Hoisted swizzle addressing: row&7 is mt-invariant (16 = 0 mod 8), so
//      GEMM ds_reads / softplus ds_writes use precomputed base addrs +
//      compile-time offset immediates instead of per-access XOR math.

typedef float  f32x4  __attribute__((ext_vector_type(4)));
typedef __bf16 bf16x8 __attribute__((ext_vector_type(8)));

// may_alias views for LDS type-punning (R5 lesson)
typedef uint32_t u32a    __attribute__((may_alias));
typedef bf16x8   bf16x8a __attribute__((may_alias));
typedef __bf16   bf16a   __attribute__((may_alias));

static constexpr int   N_TRIPLES = 2000000;
static constexpr int   DIM       = 128;
static constexpr int   NSEG      = 100000;
static constexpr int   ROWS      = 128;     // rows per block (2e6 / 128 exact)
static constexpr float LOG2F_    = 0.6931471805599453f;   // ln2
static constexpr float LOG2E_    = 1.4426950408889634f;   // 1/ln2

// base-2 softplus core: u = max(y,0) + log2(1 + 2^-|y|)
__device__ __forceinline__ float sp2_(float y) {
  float t = __builtin_amdgcn_exp2f(-__builtin_fabsf(y));  // v_exp with -abs mods
  return fmaxf(y, 0.0f) + __builtin_amdgcn_logf(1.0f + t); // v_log = log2
}

// WT1 = (W1*log2e)^T bf16 ; WT2 = W2^T bf16  (B-frags contiguous in k)
__global__ void wt_kernel(const float* __restrict__ W1, const float* __restrict__ W2,
                          __bf16* __restrict__ WT) {
  int t = blockIdx.x * 256 + threadIdx.x;   // 0..16383
  int k = t >> 7;
  int n = t & 127;
  WT[n * 128 + k]         = (__bf16)(W1[t] * LOG2E_);
  WT[16384 + n * 128 + k] = (__bf16)W2[t];
}

// b1p[n] = b1[n]*log2e ;  b2p[n] = (b2[n] - ln2*sum_k W2[k][n]) * log2e
__global__ void bias_kernel(const float* __restrict__ b1, const float* __restrict__ W2,
                            const float* __restrict__ b2,
                            float* __restrict__ b1p, float* __restrict__ b2p) {
  int n = threadIdx.x;
  float s = 0.0f;
  #pragma unroll 8
  for (int k = 0; k < 128; ++k) s += W2[k * 128 + n];
  b1p[n] = b1[n] * LOG2E_;
  b2p[n] = (b2[n] - LOG2F_ * s) * LOG2E_;
}

__global__ __launch_bounds__(512, 6) void fused_kernel(
    const float* __restrict__ dijk, const int* __restrict__ seg,
    const __bf16* __restrict__ WT,
    const float* __restrict__ b1v, const float* __restrict__ b2p,
    float* __restrict__ out)
{
  __shared__ __bf16 tile[ROWS * DIM];   // 32 KB: A, then u1, then wijk

  const int tid  = threadIdx.x;         // 0..511
  const int lane = tid & 63;
  const int wave = tid >> 6;            // 0..7 -> col slice [16w, 16w+16)
  const int l15  = lane & 15;
  const int g    = lane >> 4;           // k-group
  const int r0   = blockIdx.x * ROWS;

  char* tb = (char*)tile;

  // ---- phase 0: stage A = bf16(dijk rows) -> LDS (swizzled), cooperative ----
  {
    int row = tid >> 2, q = tid & 3;
    const float* src = dijk + (size_t)(r0 + row) * DIM + q * 32;
    char* dst = tb + row * 256;
    int swz = (row & 7) << 4;
    #pragma unroll
    for (int u = 0; u < 4; ++u) {
      f32x4 v0 = *(const f32x4*)(src + u * 8);
      f32x4 v1 = *(const f32x4*)(src + u * 8 + 4);
      bf16x8 t8;
      t8[0] = (__bf16)v0[0]; t8[1] = (__bf16)v0[1]; t8[2] = (__bf16)v0[2]; t8[3] = (__bf16)v0[3];
      t8[4] = (__bf16)v1[0]; t8[5] = (__bf16)v1[1]; t8[6] = (__bf16)v1[2]; t8[7] = (__bf16)v1[3];
      *(bf16x8a*)(dst + ((q * 64 + u * 16) ^ swz)) = t8;
    }
  }

  const int colw = wave * 16 + l15;       // this lane's output column
  const float bias1 = b1v[colw];
  const float bias2 = b2p[colw];

  // hoisted addressing (row&7 is mt-invariant since 16 % 8 == 0):
  // GEMM A-reads: row = mt*16 + l15 -> base + mt*4096, 4 ks-offsets
  const int  swA = (l15 & 7) << 4;
  const char* abase = tb + l15 * 256;
  uint32_t bo[4];
  #pragma unroll
  for (int ks = 0; ks < 4; ++ks) bo[ks] = (uint32_t)((ks * 64 + g * 16) ^ swA);
  // softplus stores: row = mt*16 + g*4 + j -> wbase[j] + mt*4096
  uint32_t wbase[4];
  #pragma unroll
  for (int j = 0; j < 4; ++j) {
    int rj = g * 4 + j;
    wbase[j] = (uint32_t)(rj * 256 + ((colw * 2) ^ ((rj & 7) << 4)));
  }

  __syncthreads();   // [1] A-tile complete

  // ---- phase 1: GEMM1 (reads A) ----
  f32x4 acc[8];
  {
    bf16x8 bf1[4];
    #pragma unroll
    for (int ks = 0; ks < 4; ++ks)
      bf1[ks] = *(const bf16x8*)(WT + colw * 128 + ks * 32 + g * 8);

    #pragma unroll
    for (int mt = 0; mt < 8; ++mt) acc[mt] = (f32x4){0.f, 0.f, 0.f, 0.f};
    #pragma unroll
    for (int mt = 0; mt < 8; ++mt) {
      const char* pm = abase + mt * 4096;
      #pragma unroll
      for (int ks = 0; ks < 4; ++ks) {
        bf16x8 a = *(const bf16x8a*)(pm + bo[ks]);
        acc[mt] = __builtin_amdgcn_mfma_f32_16x16x32_bf16(a, bf1[ks], acc[mt], 0, 0, 0);
      }
    }
  }

  __syncthreads();   // [2] all A-reads done -> tile reusable for u1

  // ---- phase 2: u1 = sp2(y1) -> tile (C/D: row = mt*16 + g*4 + j) ----
  #pragma unroll
  for (int mt = 0; mt < 8; ++mt) {
    #pragma unroll
    for (int j = 0; j < 4; ++j) {
      float u1 = sp2_(acc[mt][j] + bias1);
      *(bf16a*)(tb + wbase[j] + mt * 4096) = (__bf16)u1;
    }
  }

  __syncthreads();   // [3] u1 complete

  // ---- phase 3: GEMM2 (reads u1; W2 unscaled since ln2*log2e = 1) ----
  f32x4 acc2[8];
  {
    bf16x8 bf2[4];
    #pragma unroll
    for (int ks = 0; ks < 4; ++ks)
      bf2[ks] = *(const bf16x8*)(WT + 16384 + colw * 128 + ks * 32 + g * 8);

    #pragma unroll
    for (int mt = 0; mt < 8; ++mt) acc2[mt] = (f32x4){0.f, 0.f, 0.f, 0.f};
    #pragma unroll
    for (int mt = 0; mt < 8; ++mt) {
      const char* pm = abase + mt * 4096;
      #pragma unroll
      for (int ks = 0; ks < 4; ++ks) {
        bf16x8 a = *(const bf16x8a*)(pm + bo[ks]);
        acc2[mt] = __builtin_amdgcn_mfma_f32_16x16x32_bf16(a, bf2[ks], acc2[mt], 0, 0, 0);
      }
    }
  }

  __syncthreads();   // [4] all u1-reads done -> tile reusable for wijk

  // ---- phase 4: w = fma(sp2(y2), ln2, -ln2) -> tile ----
  #pragma unroll
  for (int mt = 0; mt < 8; ++mt) {
    #pragma unroll
    for (int j = 0; j < 4; ++j) {
      float u2 = sp2_(acc2[mt][j] + bias2);
      float wv = __builtin_fmaf(u2, LOG2F_, -LOG2F_);
      *(bf16a*)(tb + wbase[j] + mt * 4096) = (__bf16)wv;
    }
  }

  __syncthreads();   // [5] wijk complete, visible to all

  // ---- phase 5: segmented reduce (paired-column u32 form) ----
  // thread: col pair colb = (tid&63)*2, row group hh = tid>>6 -> 16 rows.
  {
    const int colb = (tid & 63) * 2;
    const int hh   = tid >> 6;           // 0..7
    const int rbeg = hh * 16;
    const int* sp = seg + r0;
    // 8 precomputed swizzled row-pointers; reads use offset:i*256 immediates
    const char* rp[8];
    #pragma unroll
    for (int k = 0; k < 8; ++k)
      rp[k] = tb + rbeg * 256 + ((colb * 2) ^ (k << 4));
    float a0 = 0.0f, a1 = 0.0f;
    int cur = sp[rbeg];
    #pragma unroll
    for (int i = 0; i < 16; ++i) {
      int s = sp[rbeg + i];
      if (s != cur) {
        atomicAdd(out + (size_t)cur * DIM + colb,     a0);
        atomicAdd(out + (size_t)cur * DIM + colb + 1, a1);
        a0 = 0.0f; a1 = 0.0f; cur = s;
      }
      uint32_t w = *(const u32a*)(rp[i & 7] + i * 256);
      a0 += __uint_as_float(w << 16);          // bf16 lo -> f32
      a1 += __uint_as_float(w & 0xffff0000u);  // bf16 hi -> f32
    }
    atomicAdd(out + (size_t)cur * DIM + colb,     a0);
    atomicAdd(out + (size_t)cur * DIM + colb + 1, a1);
  }
}

extern "C" void kernel_launch(void* const* d_in, const int* in_sizes, int n_in,
                              void* d_out, int out_size, void* d_ws, size_t ws_size,
                              hipStream_t stream) {
  const float* dijk = (const float*)d_in[0];
  const int*   seg  = (const int*)d_in[1];
  const float* W1   = (const float*)d_in[2];
  const float* b1   = (const float*)d_in[3];
  const float* W2   = (const float*)d_in[4];
  const float* b2   = (const float*)d_in[5];
  float* out = (float*)d_out;

  float*  b1p = (float*)d_ws;                       // 128 f32
  float*  b2p = (float*)((char*)d_ws + 512);        // 128 f32
  __bf16* WT  = (__bf16*)((char*)d_ws + 1024);      // 2 * 128*128 bf16 = 64 KB

  // empty segments must be exactly 0; memset re-zeroes every replay
  (void)hipMemsetAsync(out, 0, (size_t)NSEG * DIM * sizeof(float), stream);

  wt_kernel<<<64, 256, 0, stream>>>(W1, W2, WT);
  bias_kernel<<<1, 128, 0, stream>>>(b1, W2, b2, b1p, b2p);

  fused_kernel<<<N_TRIPLES / ROWS, 512, 0, stream>>>(dijk, seg, WT, b1p, b2p, out);
}